// Round 16
// baseline (99.575 us; speedup 1.0000x reference)
//
#include <hip/hip_runtime.h>

// ---------------------------------------------------------------------------
// AttentionBlock: GroupNorm -> QKV GEMM -> 32-head attention -> proj + residual
// B=4, C=512, T=2048, GROUPS=8, HEADS=8, ch=64
// ---------------------------------------------------------------------------

typedef __attribute__((ext_vector_type(8))) short short8;
typedef __attribute__((ext_vector_type(4))) float f32x4;
typedef __attribute__((ext_vector_type(16))) float f32x16;

#define T_DIM 2048
#define C_DIM 512
#define B_DIM 4

__device__ __forceinline__ float bf2f(ushort u) {
  union { unsigned int i; float f; } x; x.i = ((unsigned int)u) << 16; return x.f;
}
__device__ __forceinline__ ushort f2bf(float f) {
  union { float f; unsigned int i; } x; x.f = f;
  unsigned int i = x.i;
  return (ushort)((i + 0x7FFFu + ((i >> 16) & 1u)) >> 16);
}
__device__ __forceinline__ unsigned int cvtpk_bf16(float lo, float hi) {
  unsigned int r;
  asm("v_cvt_pk_bf16_f32 %0, %1, %2" : "=v"(r) : "v"(lo), "v"(hi));
  return r;
}
__device__ __forceinline__ float exp2_raw(float x) {
  float r;
  asm("v_exp_f32 %0, %1" : "=v"(r) : "v"(x));
  return r;
}
__device__ __forceinline__ void gl_lds16(const ushort* g, const ushort* l) {
  __builtin_amdgcn_global_load_lds(
      (const __attribute__((address_space(1))) unsigned int*)g,
      (__attribute__((address_space(3))) unsigned int*)l, 16, 0, 0);
}

#define KT_SCALE 0.1803368801f  // 0.125 * log2(e)

// ------------- prep: weight converts (1024 blocks) + gn partials (512) -----
__global__ __launch_bounds__(256) void prep_kernel(
    const float* __restrict__ qkv_w, ushort* __restrict__ wq,
    const float* __restrict__ proj_w, ushort* __restrict__ wp,
    const float* __restrict__ x, float2* __restrict__ part) {
  const int bi = blockIdx.x;
  const int tid = threadIdx.x;
  if (bi < 1024) {
    const float* s = (bi < 768) ? qkv_w : proj_w;
    ushort* d = (bi < 768) ? wq : wp;
    int i = ((bi < 768) ? bi : bi - 768) * 256 + tid;
    float4 v = ((const float4*)s)[i];
    ushort4 o;
    o.x = f2bf(v.x); o.y = f2bf(v.y); o.z = f2bf(v.z); o.w = f2bf(v.w);
    ((ushort4*)d)[i] = o;
    return;
  }
  const int pb = bi - 1024;
  const float4* p4 = (const float4*)x + (size_t)pb * 2048;
  float s = 0.f, ss = 0.f;
#pragma unroll
  for (int i = 0; i < 8; i++) {
    float4 v = p4[tid + i * 256];
    s += v.x + v.y + v.z + v.w;
    ss += v.x * v.x + v.y * v.y + v.z * v.z + v.w * v.w;
  }
  for (int off = 32; off; off >>= 1) {
    s += __shfl_xor(s, off, 64);
    ss += __shfl_xor(ss, off, 64);
  }
  __shared__ float rbuf[8];
  int w = tid >> 6, lane = tid & 63;
  if (lane == 0) { rbuf[w * 2] = s; rbuf[w * 2 + 1] = ss; }
  __syncthreads();
  if (tid == 0) {
    float S = 0.f, SS = 0.f;
#pragma unroll
    for (int i = 0; i < 4; i++) { S += rbuf[2 * i]; SS += rbuf[2 * i + 1]; }
    part[pb] = make_float2(S, SS);
  }
}

// ---------- GroupNorm apply (stats inlined from partials) -> h^T -----------
__global__ __launch_bounds__(256) void gn_apply_t_kernel(
    const float* __restrict__ x, const float* __restrict__ gw,
    const float* __restrict__ gb, const float2* __restrict__ part,
    ushort* __restrict__ ht) {
  __shared__ ushort tile[64][66];
  __shared__ float sst[2];
  const int b = blockIdx.z, gy = blockIdx.y, c0 = gy * 64, t0 = blockIdx.x * 64;
  const int tid = threadIdx.x;
  if (tid < 64) {
    float s = 0.f, ss = 0.f;
    if (tid < 16) {
      float2 p = part[(b * 8 + gy) * 16 + tid];
      s = p.x; ss = p.y;
    }
    for (int off = 8; off; off >>= 1) {
      s += __shfl_xor(s, off, 64);
      ss += __shfl_xor(ss, off, 64);
    }
    if (tid == 0) {
      float mean = s * (1.f / 131072.f);
      float var = ss * (1.f / 131072.f) - mean * mean;
      sst[0] = mean;
      sst[1] = rsqrtf(var + 1e-5f);
    }
  }
  __syncthreads();
  const float mean = sst[0], rstd = sst[1];
  {
    const int cc = tid >> 2, tc = (tid & 3) * 16;
    const int c = c0 + cc;
    float sc = rstd * gw[c];
    float bb = gb[c] - mean * sc;
    const float4* src = (const float4*)(x + ((size_t)b * 512 + c) * T_DIM + t0 + tc);
    unsigned int* dst = (unsigned int*)&tile[cc][tc];
#pragma unroll
    for (int q = 0; q < 4; q++) {
      float4 v = src[q];
      float a0 = v.x * sc + bb, a1 = v.y * sc + bb;
      float a2 = v.z * sc + bb, a3 = v.w * sc + bb;
      dst[2 * q] = (unsigned int)f2bf(a0) | ((unsigned int)f2bf(a1) << 16);
      dst[2 * q + 1] = (unsigned int)f2bf(a2) | ((unsigned int)f2bf(a3) << 16);
    }
  }
  __syncthreads();
  {
    const int tt = tid >> 2, ch = (tid & 3) * 16;
    union { uint4 v4[2]; ushort u[16]; } z;
#pragma unroll
    for (int j = 0; j < 16; j++) z.u[j] = tile[ch + j][tt];
    ushort* dst = ht + ((size_t)b * T_DIM + t0 + tt) * 512 + c0 + ch;
    *(uint4*)dst = z.v4[0];
    *(uint4*)(dst + 8) = z.v4[1];
  }
}

// --------------------- bf16 MFMA GEMM (bt, dbuf BK=32) ---------------------
// MODE 0 (QKV, MF=4): K-rows written ONLY as scaled-transposed kt[bh][t][d]
// (transk fused); others to outb. MODE 1 (proj, MF=2): f32 out+bias+residual.
// Double-buffered BK=32 k-loop (16 steps, literal buf): prefetch issued right
// after each barrier flies under the 16-MFMA compute. LDS slot swizzle
// slot=(g+row/2)&3 keeps ds_read_b128 2-way (free); source pre-swizzled,
// linear LDS dest (global_load_lds requirement).
template <int MODE, int MF>
__global__ __launch_bounds__(256, 3) void gemm_bt_kernel(
    const ushort* __restrict__ Wb, const ushort* __restrict__ Bt,
    const float* __restrict__ bias, const float* __restrict__ xres,
    ushort* __restrict__ outb, float* __restrict__ outf,
    ushort* __restrict__ ktp, int M) {
  __shared__ ushort As[2 * MF * 32 * 32];  // [buf][MF*32][32]
  __shared__ ushort Bs[2 * 128 * 32];      // [buf][128][32]
  constexpr int NY = (MODE == 0) ? 12 : 8;
  constexpr int CPX = (16 * NY * 4) >> 3;
  constexpr int ASZ = MF * 32 * 32;  // ushorts per As buf
  const int lin = blockIdx.x + 16 * (blockIdx.y + NY * blockIdx.z);
  const int wl = (lin & 7) * CPX + (lin >> 3);
  const int t0 = (wl & 15) * 128;
  const int rest = wl >> 4;
  const int o0 = (rest % NY) * (MF * 32);
  const int b = rest / NY;
  const int tid = threadIdx.x, lane = tid & 63, w = tid >> 6;
  const int li = lane & 15, g = lane >> 4;
  const int wm = (w >> 1) * (MF * 16), wn = (w & 1) * 64;
  const ushort* Bbase = Bt + (size_t)b * T_DIM * 512;

  // ---- staging geometry: lane l -> row base+l>>2, slot l&3 ----
  const int sro = lane >> 2, slot = lane & 3;
  const ushort* aW[MF / 2];
  const ushort* aB[2];
#pragma unroll
  for (int j = 0; j < MF / 2; j++) {
    int row = w * (MF * 8) + j * 16 + sro;
    int gran = (slot - (row >> 1)) & 3;
    aW[j] = Wb + (size_t)(o0 + row) * 512 + gran * 8;
  }
#pragma unroll
  for (int j = 0; j < 2; j++) {
    int row = w * 32 + j * 16 + sro;
    int gran = (slot - (row >> 1)) & 3;
    aB[j] = Bbase + (size_t)(t0 + row) * 512 + gran * 8;
  }

  f32x4 acc[MF][4];
#pragma unroll
  for (int m = 0; m < MF; m++)
#pragma unroll
    for (int n = 0; n < 4; n++) acc[m][n] = (f32x4){0.f, 0.f, 0.f, 0.f};

#define STAGE(BUF, ST)                                                        \
  {                                                                           \
    _Pragma("unroll") for (int j = 0; j < MF / 2; j++)                        \
        gl_lds16(aW[j] + (ST) * 32,                                           \
                 As + (BUF) * ASZ + (w * (MF * 8) + j * 16) * 32 + lane * 8); \
    _Pragma("unroll") for (int j = 0; j < 2; j++)                             \
        gl_lds16(aB[j] + (ST) * 32,                                           \
                 Bs + (BUF) * 4096 + (w * 32 + j * 16) * 32 + lane * 8);      \
  }

#define GSTEP(BUF)                                                            \
  {                                                                           \
    short8 af[MF], bf[4];                                                     \
    _Pragma("unroll") for (int m = 0; m < MF; m++) {                          \
      int r = wm + m * 16 + li;                                               \
      af[m] = *(const short8*)&As[(BUF) * ASZ + r * 32 +                      \
                                  (((g + (r >> 1)) & 3) << 3)];               \
    }                                                                         \
    _Pragma("unroll") for (int n = 0; n < 4; n++) {                           \
      int r = wn + n * 16 + li;                                               \
      bf[n] = *(const short8*)&Bs[(BUF) * 4096 + r * 32 +                     \
                                  (((g + (r >> 1)) & 3) << 3)];               \
    }                                                                         \
    __builtin_amdgcn_s_setprio(1);                                            \
    _Pragma("unroll") for (int m = 0; m < MF; m++)                            \
        _Pragma("unroll") for (int n = 0; n < 4; n++)                         \
            acc[m][n] = __builtin_amdgcn_mfma_f32_16x16x32_bf16(              \
                af[m], bf[n], acc[m][n], 0, 0, 0);                            \
    __builtin_amdgcn_s_setprio(0);                                            \
  }

  STAGE(0, 0);
#pragma unroll 1
  for (int s2 = 0; s2 < 8; s2++) {
    const int st = s2 * 2;
    __syncthreads();                  // buf0 ready; buf1 readers done
    if (st + 1 < 16) STAGE(1, st + 1);
    GSTEP(0);
    __syncthreads();                  // buf1 ready; buf0 readers done
    if (st + 2 < 16) STAGE(0, st + 2);
    GSTEP(1);
  }
#undef STAGE
#undef GSTEP

  size_t obase = (size_t)b * M * T_DIM;
#pragma unroll
  for (int m = 0; m < MF; m++) {
    const int om = o0 + wm + m * 16;  // 16-aligned row-group base
    bool isK = false;
    int head = 0, rem0 = 0;
    if (MODE == 0) {
      head = om / 192;
      rem0 = om - head * 192;
      isK = (rem0 >= 64 && rem0 < 128);
    }
    if (MODE == 0 && isK) {
      // fused transk: kt[bh][t][d] = scale * (qkv_k + bias)
      const int d0 = rem0 - 64 + g * 4;
      const size_t ktbase = (size_t)(b * 8 + head) * T_DIM;
      float bv0 = bias[om + g * 4 + 0];
      float bv1 = bias[om + g * 4 + 1];
      float bv2 = bias[om + g * 4 + 2];
      float bv3 = bias[om + g * 4 + 3];
#pragma unroll
      for (int n = 0; n < 4; n++) {
        int t = t0 + wn + n * 16 + li;
        ushort4 kv;
        kv.x = f2bf(KT_SCALE * (acc[m][n][0] + bv0));
        kv.y = f2bf(KT_SCALE * (acc[m][n][1] + bv1));
        kv.z = f2bf(KT_SCALE * (acc[m][n][2] + bv2));
        kv.w = f2bf(KT_SCALE * (acc[m][n][3] + bv3));
        *(ushort4*)(ktp + (ktbase + t) * 64 + d0) = kv;
      }
    } else {
#pragma unroll
      for (int r = 0; r < 4; r++) {
        int o = om + g * 4 + r;
        float bv = bias[o];
#pragma unroll
        for (int n = 0; n < 4; n++) {
          int t = t0 + wn + n * 16 + li;
          float v = acc[m][n][r] + bv;
          size_t idx = obase + (size_t)o * T_DIM + t;
          if (MODE == 0) outb[idx] = f2bf(v);
          else outf[idx] = v + xres[idx];
        }
      }
    }
  }
}

// ---------- MFMA flash attention, split-K/2 (s-halves), partial out --------
// grid (32 bh, 16 ttile, 2 shalf). 256 thr = 4 waves x 32 t-cols, 16 chunks
// of 64 keys, LDS dbuf with literal buf (unrolled x2), pointer-increment
// staging, raw v_exp_f32, coarse setprio.
__global__ __launch_bounds__(256, 4) void attn_part_kernel(
    const ushort* __restrict__ qkv, const ushort* __restrict__ Ktg,
    ushort* __restrict__ opart, float* __restrict__ lpart) {
  __shared__ ushort SH[16384];  // K:[buf*4096], V:[8192+buf*4096]
  const int bh = blockIdx.x, b = bh >> 3, hh = bh & 7;
  const int ttile = blockIdx.y;
  const int t0 = ttile * 128;
  const int shalf = blockIdx.z;
  const int tid = threadIdx.x, lane = tid & 63, w = tid >> 6;
  const int tl = lane & 31, hi = lane >> 5;
  const size_t base = ((size_t)b * 1536 + hh * 192) * (size_t)T_DIM;
  const ushort* Qp = qkv + base;
  const ushort* Vp = qkv + base + (size_t)128 * T_DIM + shalf * 1024;
  const ushort* Kp = Ktg + (size_t)bh * T_DIM * 64 + (size_t)shalf * 1024 * 64;
  const int tcol = t0 + w * 32 + tl;

  short8 qb[4];
#pragma unroll
  for (int kc = 0; kc < 4; kc++) {
    union { short8 s; ushort u[8]; } tmp;
#pragma unroll
    for (int j = 0; j < 8; j++)
      tmp.u[j] = Qp[(size_t)(kc * 16 + hi * 8 + j) * T_DIM + tcol];
    qb[kc] = tmp.s;
  }

  const int srow = lane >> 3;
  const int sblk = (lane & 7) ^ srow;

  // staging pointers, advanced by fixed strides per chunk
  const ushort* kg = Kp + (size_t)(w * 16 + srow) * 64 + sblk * 8;
  const ushort* vg = Vp + (size_t)(w * 16 + srow) * T_DIM + sblk * 8;
  const int ldW = w * 1024;  // wave-uniform LDS base component

  f32x16 zv;
#pragma unroll
  for (int r = 0; r < 16; r++) zv[r] = 0.f;
  f32x16 oacc0, oacc1;
#pragma unroll
  for (int r = 0; r < 16; r++) { oacc0[r] = 0.f; oacc1[r] = 0.f; }
  float lsum = 0.f;

  // prologue: chunk 0 -> buf 0
  gl_lds16(kg, SH + ldW);
  gl_lds16(kg + 512, SH + ldW + 512);
  gl_lds16(vg, SH + 8192 + ldW);
  gl_lds16(vg + 8 * T_DIM, SH + 8192 + ldW + 512);
  kg += 4096;
  vg += 64;

#define CHUNK(BUF, PF)                                                        \
  {                                                                           \
    __syncthreads();                                                          \
    if (PF) {                                                                 \
      gl_lds16(kg, SH + ((BUF) ^ 1) * 4096 + ldW);                            \
      gl_lds16(kg + 512, SH + ((BUF) ^ 1) * 4096 + ldW + 512);                \
      gl_lds16(vg, SH + 8192 + ((BUF) ^ 1) * 4096 + ldW);                     \
      gl_lds16(vg + 8 * T_DIM, SH + 8192 + ((BUF) ^ 1) * 4096 + ldW + 512);   \
      kg += 4096;                                                             \
      vg += 64;                                                               \
    }                                                                         \
    const ushort* kb = SH + (BUF) * 4096;                                     \
    const ushort* vb = SH + 8192 + (BUF) * 4096;                              \
    f32x16 s0, s1;                                                            \
    __builtin_amdgcn_s_setprio(1);                                            \
    _Pragma("unroll") for (int kc = 0; kc < 4; kc++) {                        \
      const int bo = (((kc * 2 + hi) ^ (tl & 7)) << 3);                       \
      short8 ak0 = *(const short8*)&kb[tl * 64 + bo];                         \
      short8 ak1 = *(const short8*)&kb[(32 + tl) * 64 + bo];                  \
      s0 = __builtin_amdgcn_mfma_f32_32x32x16_bf16(ak0, qb[kc],               \
                                                   kc == 0 ? zv : s0, 0, 0, 0);\
      s1 = __builtin_amdgcn_mfma_f32_32x32x16_bf16(ak1, qb[kc],               \
                                                   kc == 0 ? zv : s1, 0, 0, 0);\
    }                                                                         \
    __builtin_amdgcn_s_setprio(0);                                            \
    _Pragma("unroll") for (int r = 0; r < 16; r++) {                          \
      s0[r] = exp2_raw(s0[r]);                                                \
      s1[r] = exp2_raw(s1[r]);                                                \
    }                                                                         \
    {                                                                         \
      float a0 = (s0[0] + s0[1]) + (s0[2] + s0[3]);                           \
      float a1 = (s0[4] + s0[5]) + (s0[6] + s0[7]);                           \
      float a2 = (s0[8] + s0[9]) + (s0[10] + s0[11]);                         \
      float a3 = (s0[12] + s0[13]) + (s0[14] + s0[15]);                       \
      float b0 = (s1[0] + s1[1]) + (s1[2] + s1[3]);                           \
      float b1 = (s1[4] + s1[5]) + (s1[6] + s1[7]);                           \
      float b2 = (s1[8] + s1[9]) + (s1[10] + s1[11]);                         \
      float b3 = (s1[12] + s1[13]) + (s1[14] + s1[15]);                       \
      lsum += ((a0 + a1) + (a2 + a3)) + ((b0 + b1) + (b2 + b3));              \
    }                                                                         \
    unsigned int pw[2][8];                                                    \
    _Pragma("unroll") for (int p = 0; p < 8; p++) {                           \
      pw[0][p] = cvtpk_bf16(s0[2 * p], s0[2 * p + 1]);                        \
      pw[1][p] = cvtpk_bf16(s1[2 * p], s1[2 * p + 1]);                        \
    }                                                                         \
    short8 bp[4];                                                             \
    _Pragma("unroll") for (int kc = 0; kc < 4; kc++) {                        \
      const int n = kc >> 1, q = (kc & 1) * 4;                                \
      union { short8 s; unsigned int wv[4]; } bu;                             \
      _Pragma("unroll") for (int h = 0; h < 2; h++) {                         \
        unsigned int P0 = pw[n][q + h];                                       \
        unsigned int P1 = pw[n][q + 2 + h];                                   \
        asm volatile("v_permlane32_swap_b32 %0, %1" : "+v"(P0), "+v"(P1));    \
        bu.wv[h] = P0;                                                        \
        bu.wv[2 + h] = P1;                                                    \
      }                                                                       \
      bp[kc] = bu.s;                                                          \
    }                                                                         \
    __builtin_amdgcn_s_setprio(1);                                            \
    _Pragma("unroll") for (int kc = 0; kc < 4; kc++) {                        \
      const int bo = (((kc * 2 + hi) ^ (tl & 7)) << 3);                       \
      short8 av0 = *(const short8*)&vb[tl * 64 + bo];                         \
      short8 av1 = *(const short8*)&vb[(32 + tl) * 64 + bo];                  \
      oacc0 = __builtin_amdgcn_mfma_f32_32x32x16_bf16(av0, bp[kc], oacc0,     \
                                                      0, 0, 0);               \
      oacc1 = __builtin_amdgcn_mfma_f32_32x32x16_bf16(av1, bp[kc], oacc1,     \
                                                      0, 0, 0);               \
    }                                                                         \
    __builtin_amdgcn_s_setprio(0);                                            \
  }

  for (int cc = 0; cc < 8; cc++) {
    CHUNK(0, true);      // compute chunk 2cc (buf0), prefetch 2cc+1 -> buf1
    CHUNK(1, cc < 7);    // compute chunk 2cc+1 (buf1), prefetch 2cc+2 -> buf0
  }
#undef CHUNK

  // ---- write unnormalized partials ----
  const int pidx = (bh * 16 + ttile) * 2 + shalf;
  ushort* op = opart + (size_t)pidx * 8192;
#pragma unroll
  for (int r = 0; r < 16; r++) {
    int crow = (r & 3) + 8 * (r >> 2) + 4 * hi;
    op[crow * 128 + w * 32 + tl] = f2bf(oacc0[r]);
    op[(32 + crow) * 128 + w * 32 + tl] = f2bf(oacc1[r]);
  }
  float lrow = lsum + __shfl_xor(lsum, 32);
  if (hi == 0) lpart[(size_t)pidx * 128 + w * 32 + tl] = lrow;
}

// ---------------- combine halves + normalize + transpose -> a_t ------------
// grid (32 bh, 16 ttile) -- bh fastest to match attn's XCD mapping.
__global__ __launch_bounds__(256) void combine_kernel(
    const ushort* __restrict__ opart, const float* __restrict__ lpart,
    ushort* __restrict__ at) {
  __shared__ float invl[128];
  __shared__ ushort tile[128][66];
  const int bh = blockIdx.x, ttile = blockIdx.y, b = bh >> 3, hh = bh & 7;
  const int tid = threadIdx.x;
  const size_t pb = (size_t)(bh * 16 + ttile) * 2;
  const float* l0 = lpart + pb * 128;
  if (tid < 128) invl[tid] = 1.f / (l0[tid] + l0[128 + tid]);
  __syncthreads();
  {
    const int c = tid & 63, seg = tid >> 6;
    const ushort* r0 = opart + pb * 8192 + c * 128 + seg * 32;
    union { uint4 v[4]; ushort u[32]; } x0, x1;
#pragma unroll
    for (int j = 0; j < 4; j++) {
      x0.v[j] = *(const uint4*)(r0 + j * 8);
      x1.v[j] = *(const uint4*)(r0 + 8192 + j * 8);
    }
#pragma unroll
    for (int j = 0; j < 32; j++) {
      int t = seg * 32 + j;
      tile[t][c] = f2bf((bf2f(x0.u[j]) + bf2f(x1.u[j])) * invl[t]);
    }
  }
  __syncthreads();
  {
    const int t = tid >> 1, ch = (tid & 1) * 32;
    union { uint4 v[4]; ushort u[32]; } z;
#pragma unroll
    for (int j = 0; j < 32; j++) z.u[j] = tile[t][ch + j];
    uint4* dst = (uint4*)(at + ((size_t)b * T_DIM + ttile * 128 + t) * 512 +
                          hh * 64 + ch);
#pragma unroll
    for (int j = 0; j < 4; j++) dst[j] = z.v[j];
  }
}

// ---------------------------------------------------------------------------
extern "C" void kernel_launch(void* const* d_in, const int* in_sizes, int n_in,
                              void* d_out, int out_size, void* d_ws,
                              size_t ws_size, hipStream_t stream) {
  const float* x = (const float*)d_in[0];
  const float* gn_w = (const float*)d_in[1];
  const float* gn_b = (const float*)d_in[2];
  const float* qkv_w = (const float*)d_in[3];
  const float* qkv_b = (const float*)d_in[4];
  const float* proj_w = (const float*)d_in[5];
  const float* proj_b = (const float*)d_in[6];
  float* out = (float*)d_out;

  char* ws = (char*)d_ws;
  float2* part = (float2*)ws;                              // 4 KB
  ushort* ht_bf = (ushort*)(ws + 8192);                    // 8 MB (reused as a_t)
  ushort* at_bf = ht_bf;
  ushort* qkv_bf = (ushort*)(ws + 8192 + 8388608);                        // 24 MB
  ushort* wq_bf = (ushort*)(ws + 8192 + 8388608 + 25165824);              // 1.5 MB
  ushort* wp_bf = (ushort*)(ws + 8192 + 8388608 + 25165824 + 1572864);    // 0.5 MB
  ushort* kt_bf = (ushort*)(ws + 8192 + 8388608 + 25165824 + 1572864 + 524288);  // 8 MB
  ushort* op_bf = (ushort*)(ws + 8192 + 8388608 + 25165824 + 1572864 + 524288 +
                            8388608);                      // 16 MB partial O
  float* lp_f = (float*)(ws + 8192 + 8388608 + 25165824 + 1572864 + 524288 +
                         8388608 + 16777216);              // 512 KB partial l

  prep_kernel<<<1536, 256, 0, stream>>>(qkv_w, wq_bf, proj_w, wp_bf, x, part);
  gn_apply_t_kernel<<<dim3(32, 8, 4), 256, 0, stream>>>(x, gn_w, gn_b, part, ht_bf);
  gemm_bt_kernel<0, 4><<<dim3(16, 12, 4), 256, 0, stream>>>(
      wq_bf, ht_bf, qkv_b, nullptr, qkv_bf, nullptr, kt_bf, 1536);
  attn_part_kernel<<<dim3(32, 16, 2), 256, 0, stream>>>(qkv_bf, kt_bf, op_bf, lp_f);
  combine_kernel<<<dim3(32, 16), 256, 0, stream>>>(op_bf, lp_f, at_bf);
  gemm_bt_kernel<1, 2><<<dim3(16, 8, 4), 256, 0, stream>>>(
      wp_bf, at_bf, proj_b, x, nullptr, out, nullptr, 512);
}

// Round 17
// 95.388 us; speedup vs baseline: 1.0439x; 1.0439x over previous
//
#include <hip/hip_runtime.h>

// ---------------------------------------------------------------------------
// AttentionBlock: GroupNorm -> QKV GEMM -> 32-head attention -> proj + residual
// B=4, C=512, T=2048, GROUPS=8, HEADS=8, ch=64
// ---------------------------------------------------------------------------

typedef __attribute__((ext_vector_type(8))) short short8;
typedef __attribute__((ext_vector_type(4))) float f32x4;
typedef __attribute__((ext_vector_type(16))) float f32x16;

#define T_DIM 2048
#define C_DIM 512
#define B_DIM 4

__device__ __forceinline__ float bf2f(ushort u) {
  union { unsigned int i; float f; } x; x.i = ((unsigned int)u) << 16; return x.f;
}
__device__ __forceinline__ ushort f2bf(float f) {
  union { float f; unsigned int i; } x; x.f = f;
  unsigned int i = x.i;
  return (ushort)((i + 0x7FFFu + ((i >> 16) & 1u)) >> 16);
}
__device__ __forceinline__ unsigned int cvtpk_bf16(float lo, float hi) {
  unsigned int r;
  asm("v_cvt_pk_bf16_f32 %0, %1, %2" : "=v"(r) : "v"(lo), "v"(hi));
  return r;
}
__device__ __forceinline__ float exp2_raw(float x) {
  float r;
  asm("v_exp_f32 %0, %1" : "=v"(r) : "v"(x));
  return r;
}
__device__ __forceinline__ void gl_lds16(const ushort* g, const ushort* l) {
  __builtin_amdgcn_global_load_lds(
      (const __attribute__((address_space(1))) unsigned int*)g,
      (__attribute__((address_space(3))) unsigned int*)l, 16, 0, 0);
}

#define KT_SCALE 0.1803368801f  // 0.125 * log2(e)

// ------------- prep: weight converts (1024 blocks) + gn partials (512) -----
__global__ __launch_bounds__(256) void prep_kernel(
    const float* __restrict__ qkv_w, ushort* __restrict__ wq,
    const float* __restrict__ proj_w, ushort* __restrict__ wp,
    const float* __restrict__ x, float2* __restrict__ part) {
  const int bi = blockIdx.x;
  const int tid = threadIdx.x;
  if (bi < 1024) {
    const float* s = (bi < 768) ? qkv_w : proj_w;
    ushort* d = (bi < 768) ? wq : wp;
    int i = ((bi < 768) ? bi : bi - 768) * 256 + tid;
    float4 v = ((const float4*)s)[i];
    ushort4 o;
    o.x = f2bf(v.x); o.y = f2bf(v.y); o.z = f2bf(v.z); o.w = f2bf(v.w);
    ((ushort4*)d)[i] = o;
    return;
  }
  const int pb = bi - 1024;
  const float4* p4 = (const float4*)x + (size_t)pb * 2048;
  float s = 0.f, ss = 0.f;
#pragma unroll
  for (int i = 0; i < 8; i++) {
    float4 v = p4[tid + i * 256];
    s += v.x + v.y + v.z + v.w;
    ss += v.x * v.x + v.y * v.y + v.z * v.z + v.w * v.w;
  }
  for (int off = 32; off; off >>= 1) {
    s += __shfl_xor(s, off, 64);
    ss += __shfl_xor(ss, off, 64);
  }
  __shared__ float rbuf[8];
  int w = tid >> 6, lane = tid & 63;
  if (lane == 0) { rbuf[w * 2] = s; rbuf[w * 2 + 1] = ss; }
  __syncthreads();
  if (tid == 0) {
    float S = 0.f, SS = 0.f;
#pragma unroll
    for (int i = 0; i < 4; i++) { S += rbuf[2 * i]; SS += rbuf[2 * i + 1]; }
    part[pb] = make_float2(S, SS);
  }
}

// ---------- GroupNorm apply (stats inlined from partials) -> h^T -----------
__global__ __launch_bounds__(256) void gn_apply_t_kernel(
    const float* __restrict__ x, const float* __restrict__ gw,
    const float* __restrict__ gb, const float2* __restrict__ part,
    ushort* __restrict__ ht) {
  __shared__ ushort tile[64][66];
  __shared__ float sst[2];
  const int b = blockIdx.z, gy = blockIdx.y, c0 = gy * 64, t0 = blockIdx.x * 64;
  const int tid = threadIdx.x;
  if (tid < 64) {
    float s = 0.f, ss = 0.f;
    if (tid < 16) {
      float2 p = part[(b * 8 + gy) * 16 + tid];
      s = p.x; ss = p.y;
    }
    for (int off = 8; off; off >>= 1) {
      s += __shfl_xor(s, off, 64);
      ss += __shfl_xor(ss, off, 64);
    }
    if (tid == 0) {
      float mean = s * (1.f / 131072.f);
      float var = ss * (1.f / 131072.f) - mean * mean;
      sst[0] = mean;
      sst[1] = rsqrtf(var + 1e-5f);
    }
  }
  __syncthreads();
  const float mean = sst[0], rstd = sst[1];
  {
    const int cc = tid >> 2, tc = (tid & 3) * 16;
    const int c = c0 + cc;
    float sc = rstd * gw[c];
    float bb = gb[c] - mean * sc;
    const float4* src = (const float4*)(x + ((size_t)b * 512 + c) * T_DIM + t0 + tc);
    unsigned int* dst = (unsigned int*)&tile[cc][tc];
#pragma unroll
    for (int q = 0; q < 4; q++) {
      float4 v = src[q];
      float a0 = v.x * sc + bb, a1 = v.y * sc + bb;
      float a2 = v.z * sc + bb, a3 = v.w * sc + bb;
      dst[2 * q] = (unsigned int)f2bf(a0) | ((unsigned int)f2bf(a1) << 16);
      dst[2 * q + 1] = (unsigned int)f2bf(a2) | ((unsigned int)f2bf(a3) << 16);
    }
  }
  __syncthreads();
  {
    const int tt = tid >> 2, ch = (tid & 3) * 16;
    union { uint4 v4[2]; ushort u[16]; } z;
#pragma unroll
    for (int j = 0; j < 16; j++) z.u[j] = tile[ch + j][tt];
    ushort* dst = ht + ((size_t)b * T_DIM + t0 + tt) * 512 + c0 + ch;
    *(uint4*)dst = z.v4[0];
    *(uint4*)(dst + 8) = z.v4[1];
  }
}

// --------------------- bf16 MFMA GEMM (bt-structure) -----------------------
// MODE 0 (QKV, MF=4): K-rows written ONLY as scaled-transposed kt[bh][t][d]
// (transk fused); others to outb. MODE 1 (proj, MF=2): f32 out+bias+residual.
// XCD-aware bijective block swizzle: XCD j gets a contiguous (b, o-range)
// chunk sharing one batch's B-panel in its L2. BK=64, 2 barriers/step,
// 32 MFMA/wave/step (proven optimum vs BK=32 dbuf, r16).
template <int MODE, int MF>
__global__ __launch_bounds__(256, 3) void gemm_bt_kernel(
    const ushort* __restrict__ Wb, const ushort* __restrict__ Bt,
    const float* __restrict__ bias, const float* __restrict__ xres,
    ushort* __restrict__ outb, float* __restrict__ outf,
    ushort* __restrict__ ktp, int M) {
  __shared__ ushort As[MF * 32 * 64];
  __shared__ ushort Bs[128 * 64];
  constexpr int NY = (MODE == 0) ? 12 : 8;
  constexpr int CPX = (16 * NY * 4) >> 3;
  const int lin = blockIdx.x + 16 * (blockIdx.y + NY * blockIdx.z);
  const int wl = (lin & 7) * CPX + (lin >> 3);
  const int t0 = (wl & 15) * 128;
  const int rest = wl >> 4;
  const int o0 = (rest % NY) * (MF * 32);
  const int b = rest / NY;
  const int tid = threadIdx.x, lane = tid & 63, w = tid >> 6;
  const int li = lane & 15, g = lane >> 4;
  const int wm = (w >> 1) * (MF * 16), wn = (w & 1) * 64;
  const int r8 = tid >> 3, bl = tid & 7;
  const ushort* Bbase = Bt + (size_t)b * T_DIM * 512;

  f32x4 acc[MF][4];
#pragma unroll
  for (int m = 0; m < MF; m++)
#pragma unroll
    for (int n = 0; n < 4; n++) acc[m][n] = (f32x4){0.f, 0.f, 0.f, 0.f};

  for (int ks = 0; ks < 8; ks++) {
    const int k0 = ks * 64;
#pragma unroll
    for (int i = 0; i < 4; i++) {
      int row = i * 32 + r8;
      int sb = (bl ^ (row & 7)) << 3;
      if (i < MF)
        gl_lds16(Wb + (size_t)(o0 + row) * 512 + k0 + sb, As + row * 64 + bl * 8);
      gl_lds16(Bbase + (size_t)(t0 + row) * 512 + k0 + sb, Bs + row * 64 + bl * 8);
    }
    __syncthreads();
#pragma unroll
    for (int kk = 0; kk < 2; kk++) {
      short8 af[MF], bf[4];
#pragma unroll
      for (int m = 0; m < MF; m++)
        af[m] = *(const short8*)&As[(wm + m * 16 + li) * 64 +
                                    (((kk * 4 + g) ^ (li & 7)) << 3)];
#pragma unroll
      for (int n = 0; n < 4; n++)
        bf[n] = *(const short8*)&Bs[(wn + n * 16 + li) * 64 +
                                    (((kk * 4 + g) ^ (li & 7)) << 3)];
      __builtin_amdgcn_s_setprio(1);
#pragma unroll
      for (int m = 0; m < MF; m++)
#pragma unroll
        for (int n = 0; n < 4; n++)
          acc[m][n] = __builtin_amdgcn_mfma_f32_16x16x32_bf16(af[m], bf[n],
                                                              acc[m][n], 0, 0, 0);
      __builtin_amdgcn_s_setprio(0);
    }
    __syncthreads();
  }

  size_t obase = (size_t)b * M * T_DIM;
#pragma unroll
  for (int m = 0; m < MF; m++) {
    const int om = o0 + wm + m * 16;  // 16-aligned row-group base
    bool isK = false;
    int head = 0, rem0 = 0;
    if (MODE == 0) {
      head = om / 192;
      rem0 = om - head * 192;
      isK = (rem0 >= 64 && rem0 < 128);
    }
    if (MODE == 0 && isK) {
      // fused transk: kt[bh][t][d] = scale * (qkv_k + bias)
      const int d0 = rem0 - 64 + g * 4;
      const size_t ktbase = (size_t)(b * 8 + head) * T_DIM;
      float bv0 = bias[om + g * 4 + 0];
      float bv1 = bias[om + g * 4 + 1];
      float bv2 = bias[om + g * 4 + 2];
      float bv3 = bias[om + g * 4 + 3];
#pragma unroll
      for (int n = 0; n < 4; n++) {
        int t = t0 + wn + n * 16 + li;
        ushort4 kv;
        kv.x = f2bf(KT_SCALE * (acc[m][n][0] + bv0));
        kv.y = f2bf(KT_SCALE * (acc[m][n][1] + bv1));
        kv.z = f2bf(KT_SCALE * (acc[m][n][2] + bv2));
        kv.w = f2bf(KT_SCALE * (acc[m][n][3] + bv3));
        *(ushort4*)(ktp + (ktbase + t) * 64 + d0) = kv;
      }
    } else {
#pragma unroll
      for (int r = 0; r < 4; r++) {
        int o = om + g * 4 + r;
        float bv = bias[o];
#pragma unroll
        for (int n = 0; n < 4; n++) {
          int t = t0 + wn + n * 16 + li;
          float v = acc[m][n][r] + bv;
          size_t idx = obase + (size_t)o * T_DIM + t;
          if (MODE == 0) outb[idx] = f2bf(v);
          else outf[idx] = v + xres[idx];
        }
      }
    }
  }
}

// ---------- MFMA flash attention, split-K/2 (s-halves), partial out --------
// grid (32 bh, 16 ttile, 2 shalf). 256 thr = 4 waves x 32 t-cols, 16 chunks
// of 64 keys, LDS dbuf with literal buf (unrolled x2), pointer-increment
// staging, raw v_exp_f32, coarse setprio.
__global__ __launch_bounds__(256, 4) void attn_part_kernel(
    const ushort* __restrict__ qkv, const ushort* __restrict__ Ktg,
    ushort* __restrict__ opart, float* __restrict__ lpart) {
  __shared__ ushort SH[16384];  // K:[buf*4096], V:[8192+buf*4096]
  const int bh = blockIdx.x, b = bh >> 3, hh = bh & 7;
  const int ttile = blockIdx.y;
  const int t0 = ttile * 128;
  const int shalf = blockIdx.z;
  const int tid = threadIdx.x, lane = tid & 63, w = tid >> 6;
  const int tl = lane & 31, hi = lane >> 5;
  const size_t base = ((size_t)b * 1536 + hh * 192) * (size_t)T_DIM;
  const ushort* Qp = qkv + base;
  const ushort* Vp = qkv + base + (size_t)128 * T_DIM + shalf * 1024;
  const ushort* Kp = Ktg + (size_t)bh * T_DIM * 64 + (size_t)shalf * 1024 * 64;
  const int tcol = t0 + w * 32 + tl;

  short8 qb[4];
#pragma unroll
  for (int kc = 0; kc < 4; kc++) {
    union { short8 s; ushort u[8]; } tmp;
#pragma unroll
    for (int j = 0; j < 8; j++)
      tmp.u[j] = Qp[(size_t)(kc * 16 + hi * 8 + j) * T_DIM + tcol];
    qb[kc] = tmp.s;
  }

  const int srow = lane >> 3;
  const int sblk = (lane & 7) ^ srow;

  // staging pointers, advanced by fixed strides per chunk
  const ushort* kg = Kp + (size_t)(w * 16 + srow) * 64 + sblk * 8;
  const ushort* vg = Vp + (size_t)(w * 16 + srow) * T_DIM + sblk * 8;
  const int ldW = w * 1024;  // wave-uniform LDS base component

  f32x16 zv;
#pragma unroll
  for (int r = 0; r < 16; r++) zv[r] = 0.f;
  f32x16 oacc0, oacc1;
#pragma unroll
  for (int r = 0; r < 16; r++) { oacc0[r] = 0.f; oacc1[r] = 0.f; }
  float lsum = 0.f;

  // prologue: chunk 0 -> buf 0
  gl_lds16(kg, SH + ldW);
  gl_lds16(kg + 512, SH + ldW + 512);
  gl_lds16(vg, SH + 8192 + ldW);
  gl_lds16(vg + 8 * T_DIM, SH + 8192 + ldW + 512);
  kg += 4096;
  vg += 64;

#define CHUNK(BUF, PF)                                                        \
  {                                                                           \
    __syncthreads();                                                          \
    if (PF) {                                                                 \
      gl_lds16(kg, SH + ((BUF) ^ 1) * 4096 + ldW);                            \
      gl_lds16(kg + 512, SH + ((BUF) ^ 1) * 4096 + ldW + 512);                \
      gl_lds16(vg, SH + 8192 + ((BUF) ^ 1) * 4096 + ldW);                     \
      gl_lds16(vg + 8 * T_DIM, SH + 8192 + ((BUF) ^ 1) * 4096 + ldW + 512);   \
      kg += 4096;                                                             \
      vg += 64;                                                               \
    }                                                                         \
    const ushort* kb = SH + (BUF) * 4096;                                     \
    const ushort* vb = SH + 8192 + (BUF) * 4096;                              \
    f32x16 s0, s1;                                                            \
    __builtin_amdgcn_s_setprio(1);                                            \
    _Pragma("unroll") for (int kc = 0; kc < 4; kc++) {                        \
      const int bo = (((kc * 2 + hi) ^ (tl & 7)) << 3);                       \
      short8 ak0 = *(const short8*)&kb[tl * 64 + bo];                         \
      short8 ak1 = *(const short8*)&kb[(32 + tl) * 64 + bo];                  \
      s0 = __builtin_amdgcn_mfma_f32_32x32x16_bf16(ak0, qb[kc],               \
                                                   kc == 0 ? zv : s0, 0, 0, 0);\
      s1 = __builtin_amdgcn_mfma_f32_32x32x16_bf16(ak1, qb[kc],               \
                                                   kc == 0 ? zv : s1, 0, 0, 0);\
    }                                                                         \
    __builtin_amdgcn_s_setprio(0);                                            \
    _Pragma("unroll") for (int r = 0; r < 16; r++) {                          \
      s0[r] = exp2_raw(s0[r]);                                                \
      s1[r] = exp2_raw(s1[r]);                                                \
    }                                                                         \
    {                                                                         \
      float a0 = (s0[0] + s0[1]) + (s0[2] + s0[3]);                           \
      float a1 = (s0[4] + s0[5]) + (s0[6] + s0[7]);                           \
      float a2 = (s0[8] + s0[9]) + (s0[10] + s0[11]);                         \
      float a3 = (s0[12] + s0[13]) + (s0[14] + s0[15]);                       \
      float b0 = (s1[0] + s1[1]) + (s1[2] + s1[3]);                           \
      float b1 = (s1[4] + s1[5]) + (s1[6] + s1[7]);                           \
      float b2 = (s1[8] + s1[9]) + (s1[10] + s1[11]);                         \
      float b3 = (s1[12] + s1[13]) + (s1[14] + s1[15]);                       \
      lsum += ((a0 + a1) + (a2 + a3)) + ((b0 + b1) + (b2 + b3));              \
    }                                                                         \
    unsigned int pw[2][8];                                                    \
    _Pragma("unroll") for (int p = 0; p < 8; p++) {                           \
      pw[0][p] = cvtpk_bf16(s0[2 * p], s0[2 * p + 1]);                        \
      pw[1][p] = cvtpk_bf16(s1[2 * p], s1[2 * p + 1]);                        \
    }                                                                         \
    short8 bp[4];                                                             \
    _Pragma("unroll") for (int kc = 0; kc < 4; kc++) {                        \
      const int n = kc >> 1, q = (kc & 1) * 4;                                \
      union { short8 s; unsigned int wv[4]; } bu;                             \
      _Pragma("unroll") for (int h = 0; h < 2; h++) {                         \
        unsigned int P0 = pw[n][q + h];                                       \
        unsigned int P1 = pw[n][q + 2 + h];                                   \
        asm volatile("v_permlane32_swap_b32 %0, %1" : "+v"(P0), "+v"(P1));    \
        bu.wv[h] = P0;                                                        \
        bu.wv[2 + h] = P1;                                                    \
      }                                                                       \
      bp[kc] = bu.s;                                                          \
    }                                                                         \
    __builtin_amdgcn_s_setprio(1);                                            \
    _Pragma("unroll") for (int kc = 0; kc < 4; kc++) {                        \
      const int bo = (((kc * 2 + hi) ^ (tl & 7)) << 3);                       \
      short8 av0 = *(const short8*)&vb[tl * 64 + bo];                         \
      short8 av1 = *(const short8*)&vb[(32 + tl) * 64 + bo];                  \
      oacc0 = __builtin_amdgcn_mfma_f32_32x32x16_bf16(av0, bp[kc], oacc0,     \
                                                      0, 0, 0);               \
      oacc1 = __builtin_amdgcn_mfma_f32_32x32x16_bf16(av1, bp[kc], oacc1,     \
                                                      0, 0, 0);               \
    }                                                                         \
    __builtin_amdgcn_s_setprio(0);                                            \
  }

  for (int cc = 0; cc < 8; cc++) {
    CHUNK(0, true);      // compute chunk 2cc (buf0), prefetch 2cc+1 -> buf1
    CHUNK(1, cc < 7);    // compute chunk 2cc+1 (buf1), prefetch 2cc+2 -> buf0
  }
#undef CHUNK

  // ---- write unnormalized partials ----
  const int pidx = (bh * 16 + ttile) * 2 + shalf;
  ushort* op = opart + (size_t)pidx * 8192;
#pragma unroll
  for (int r = 0; r < 16; r++) {
    int crow = (r & 3) + 8 * (r >> 2) + 4 * hi;
    op[crow * 128 + w * 32 + tl] = f2bf(oacc0[r]);
    op[(32 + crow) * 128 + w * 32 + tl] = f2bf(oacc1[r]);
  }
  float lrow = lsum + __shfl_xor(lsum, 32);
  if (hi == 0) lpart[(size_t)pidx * 128 + w * 32 + tl] = lrow;
}

// ---------------- combine halves + normalize + transpose -> a_t ------------
// grid (32 bh, 16 ttile) -- bh fastest to match attn's XCD mapping.
__global__ __launch_bounds__(256) void combine_kernel(
    const ushort* __restrict__ opart, const float* __restrict__ lpart,
    ushort* __restrict__ at) {
  __shared__ float invl[128];
  __shared__ ushort tile[128][66];
  const int bh = blockIdx.x, ttile = blockIdx.y, b = bh >> 3, hh = bh & 7;
  const int tid = threadIdx.x;
  const size_t pb = (size_t)(bh * 16 + ttile) * 2;
  const float* l0 = lpart + pb * 128;
  if (tid < 128) invl[tid] = 1.f / (l0[tid] + l0[128 + tid]);
  __syncthreads();
  {
    const int c = tid & 63, seg = tid >> 6;
    const ushort* r0 = opart + pb * 8192 + c * 128 + seg * 32;
    union { uint4 v[4]; ushort u[32]; } x0, x1;
#pragma unroll
    for (int j = 0; j < 4; j++) {
      x0.v[j] = *(const uint4*)(r0 + j * 8);
      x1.v[j] = *(const uint4*)(r0 + 8192 + j * 8);
    }
#pragma unroll
    for (int j = 0; j < 32; j++) {
      int t = seg * 32 + j;
      tile[t][c] = f2bf((bf2f(x0.u[j]) + bf2f(x1.u[j])) * invl[t]);
    }
  }
  __syncthreads();
  {
    const int t = tid >> 1, ch = (tid & 1) * 32;
    union { uint4 v[4]; ushort u[32]; } z;
#pragma unroll
    for (int j = 0; j < 32; j++) z.u[j] = tile[t][ch + j];
    uint4* dst = (uint4*)(at + ((size_t)b * T_DIM + ttile * 128 + t) * 512 +
                          hh * 64 + ch);
#pragma unroll
    for (int j = 0; j < 4; j++) dst[j] = z.v[j];
  }
}

// ---------------------------------------------------------------------------
extern "C" void kernel_launch(void* const* d_in, const int* in_sizes, int n_in,
                              void* d_out, int out_size, void* d_ws,
                              size_t ws_size, hipStream_t stream) {
  const float* x = (const float*)d_in[0];
  const float* gn_w = (const float*)d_in[1];
  const float* gn_b = (const float*)d_in[2];
  const float* qkv_w = (const float*)d_in[3];
  const float* qkv_b = (const float*)d_in[4];
  const float* proj_w = (const float*)d_in[5];
  const float* proj_b = (const float*)d_in[6];
  float* out = (float*)d_out;

  char* ws = (char*)d_ws;
  float2* part = (float2*)ws;                              // 4 KB
  ushort* ht_bf = (ushort*)(ws + 8192);                    // 8 MB (reused as a_t)
  ushort* at_bf = ht_bf;
  ushort* qkv_bf = (ushort*)(ws + 8192 + 8388608);                        // 24 MB
  ushort* wq_bf = (ushort*)(ws + 8192 + 8388608 + 25165824);              // 1.5 MB
  ushort* wp_bf = (ushort*)(ws + 8192 + 8388608 + 25165824 + 1572864);    // 0.5 MB
  ushort* kt_bf = (ushort*)(ws + 8192 + 8388608 + 25165824 + 1572864 + 524288);  // 8 MB
  ushort* op_bf = (ushort*)(ws + 8192 + 8388608 + 25165824 + 1572864 + 524288 +
                            8388608);                      // 16 MB partial O
  float* lp_f = (float*)(ws + 8192 + 8388608 + 25165824 + 1572864 + 524288 +
                         8388608 + 16777216);              // 512 KB partial l

  prep_kernel<<<1536, 256, 0, stream>>>(qkv_w, wq_bf, proj_w, wp_bf, x, part);
  gn_apply_t_kernel<<<dim3(32, 8, 4), 256, 0, stream>>>(x, gn_w, gn_b, part, ht_bf);
  gemm_bt_kernel<0, 4><<<dim3(16, 12, 4), 256, 0, stream>>>(
      wq_bf, ht_bf, qkv_b, nullptr, qkv_bf, nullptr, kt_bf, 1536);
  attn_part_kernel<<<dim3(32, 16, 2), 256, 0, stream>>>(qkv_bf, kt_bf, op_bf, lp_f);
  combine_kernel<<<dim3(32, 16), 256, 0, stream>>>(op_bf, lp_f, at_bf);
  gemm_bt_kernel<1, 2><<<dim3(16, 8, 4), 256, 0, stream>>>(
      wp_bf, at_bf, proj_b, x, nullptr, out, nullptr, 512);
}